// Round 3
// baseline (593.558 us; speedup 1.0000x reference)
//
#include <hip/hip_runtime.h>
#include <math.h>

#define N_PIX 1024
#define NV 64
#define CUBE_ELEMS (NV * N_PIX * N_PIX)  // 67,108,864 voxels (256 MB fp32)

// ---------------- scatter: points -> cube (atomicAdd) ----------------
// Index math must bit-match the XLA-jitted reference:
//  * x/y: XLA folds the constant divide into multiply-by-reciprocal:
//         (c + 51.15f) * 10.0f   (fp64 1/0.1 rounds to exactly 10.0f)
//  * v:   dv is traced (vel_axis is an argument), so XLA keeps a true
//         correctly-rounded fp32 division.
// R1 (fp32 div chain) and R2 (fp64 chain) both showed ~0.134*f single-pixel
// misplacements (~50 boundary straddlers) — the recip-mul chain explains both.
__global__ __launch_bounds__(256) void splat_scatter(
    const float2* __restrict__ pos,       // (M,2) ra,dec interleaved
    const float*  __restrict__ vel_chan,  // (M,)
    const float*  __restrict__ flux,      // (M,)
    const float*  __restrict__ vel_axis,  // (NV,)
    float* __restrict__ cube, int M)
{
    int i = blockIdx.x * blockDim.x + threadIdx.x;
    if (i >= M) return;

    const float FOV_HALF = 51.15f;        // f32(51.150000000000006)
    const float INV_PIX  = 10.0f;         // f32(1/0.1) == 10.0f exactly
    const float vel0 = vel_axis[0];       // -400.0f (exact)
    const float dv   = vel_axis[1] - vel0; // 12.5f (exact)

    float2 p = pos[i];
    float  v = vel_chan[i];
    float  f = flux[i];

    int ix0 = (int)floorf((p.x + FOV_HALF) * INV_PIX);
    int iy0 = (int)floorf((p.y + FOV_HALF) * INV_PIX);
    int iv0 = (int)floorf((v - vel0) / dv);   // fp32 IEEE division (dv traced)

    const int margin = 4;  // kernel2d.shape[-1]//2 + 1
    bool mask = (ix0 >= -margin) && (ix0 < N_PIX + margin)
             && (iy0 >= -margin) && (iy0 < N_PIX + margin)
             && (iv0 >= 0) && (iv0 < NV);
    if (!mask) return;  // masked points add 0.0 in the reference — a no-op

    // Reference flattens in int32 and drops only flat-OOB indices; negative ix
    // aliases into the previous row exactly like this arithmetic does.
    int idx = (iv0 * N_PIX + iy0) * N_PIX + ix0;
    if (idx >= 0 && idx < CUBE_ELEMS)
        atomicAdd(cube + idx, f);
}

// ---------------- separable 7x7 conv via LDS ----------------
#define TX 64
#define TY 16
#define HALO 3
#define RAW_W (TX + 2 * HALO)  // 70
#define RAW_H (TY + 2 * HALO)  // 22

__global__ __launch_bounds__(256) void conv7x7(
    const float* __restrict__ cube,
    const float* __restrict__ k2d,   // (7,7) flat, = outer(g,g)
    float* __restrict__ out)
{
    __shared__ float raw[RAW_H][RAW_W];   // input tile + halo
    __shared__ float hbuf[RAW_H][TX];     // after horizontal pass

    // Recover the 1-D kernel from row 3: k2d[3][j] = g3*g[j], k2d[3][3] = g3^2.
    float g[7];
    {
        float g3 = sqrtf(k2d[24]);
        #pragma unroll
        for (int j = 0; j < 7; ++j) g[j] = k2d[21 + j] / g3;
    }

    const int tid = threadIdx.y * 64 + threadIdx.x;
    const int x0 = blockIdx.x * TX;
    const int y0 = blockIdx.y * TY;
    const int v  = blockIdx.z;
    const float* __restrict__ src = cube + (size_t)v * (N_PIX * N_PIX);

    // Load 70x22 region (zero-padded at image borders).
    for (int l = tid; l < RAW_H * RAW_W; l += 256) {
        int r = l / RAW_W, c = l - r * RAW_W;
        int gx = x0 - HALO + c;
        int gy = y0 - HALO + r;
        float val = 0.0f;
        if (gx >= 0 && gx < N_PIX && gy >= 0 && gy < N_PIX)
            val = src[gy * N_PIX + gx];
        raw[r][c] = val;
    }
    __syncthreads();

    // Horizontal pass: 64 x 22 results.
    for (int l = tid; l < RAW_H * TX; l += 256) {
        int r = l >> 6, c = l & 63;
        float s = 0.0f;
        #pragma unroll
        for (int j = 0; j < 7; ++j) s = fmaf(raw[r][c + j], g[j], s);
        hbuf[r][c] = s;
    }
    __syncthreads();

    // Vertical pass + coalesced store (each thread: 4 rows of its column).
    float* __restrict__ dst =
        out + (size_t)v * (N_PIX * N_PIX) + (size_t)y0 * N_PIX + x0 + threadIdx.x;
    #pragma unroll
    for (int i = 0; i < 4; ++i) {
        int row = threadIdx.y * 4 + i;          // 0..15
        float s = 0.0f;
        #pragma unroll
        for (int j = 0; j < 7; ++j) s = fmaf(hbuf[row + j][threadIdx.x], g[j], s);
        dst[(size_t)row * N_PIX] = s;
    }
}

extern "C" void kernel_launch(void* const* d_in, const int* in_sizes, int n_in,
                              void* d_out, int out_size, void* d_ws, size_t ws_size,
                              hipStream_t stream)
{
    const float2* pos      = (const float2*)d_in[0];  // (200000,8,2)
    const float*  vel_chan = (const float*)d_in[1];   // (200000,8)
    const float*  flux     = (const float*)d_in[2];   // (200000,8)
    const float*  vel_axis = (const float*)d_in[3];   // (64,)
    const float*  k2d      = (const float*)d_in[4];   // (1,1,7,7)
    float* cube = (float*)d_ws;                        // 256 MB scratch cube
    float* out  = (float*)d_out;

    const int M = in_sizes[1];  // 1,600,000 points

    // d_ws is re-poisoned to 0xAA before every timed launch — zero the cube.
    hipMemsetAsync(cube, 0, (size_t)CUBE_ELEMS * sizeof(float), stream);

    splat_scatter<<<(M + 255) / 256, 256, 0, stream>>>(
        pos, vel_chan, flux, vel_axis, cube, M);

    dim3 grid(N_PIX / TX, N_PIX / TY, NV);
    conv7x7<<<grid, dim3(64, 4), 0, stream>>>(cube, k2d, out);
}

// Round 4
// 507.710 us; speedup vs baseline: 1.1691x; 1.1691x over previous
//
#include <hip/hip_runtime.h>
#include <math.h>

#define N_PIX 1024
#define NV 64
#define CUBE_ELEMS (NV * N_PIX * N_PIX)  // 67,108,864 voxels (256 MB fp32)

// ---------------- scatter: points -> cube (atomicAdd) ----------------
// Index math bit-matches the XLA-jitted reference (verified R3, absmax 2e-3):
//  * x/y: constant divide folded to multiply-by-reciprocal: (c+51.15f)*10.0f
//  * v:   dv traced -> true fp32 IEEE division
__global__ __launch_bounds__(256) void splat_scatter(
    const float2* __restrict__ pos,
    const float*  __restrict__ vel_chan,
    const float*  __restrict__ flux,
    const float*  __restrict__ vel_axis,
    float* __restrict__ cube, int M)
{
    int i = blockIdx.x * blockDim.x + threadIdx.x;
    if (i >= M) return;

    const float FOV_HALF = 51.15f;
    const float INV_PIX  = 10.0f;
    const float vel0 = vel_axis[0];
    const float dv   = vel_axis[1] - vel0;

    float2 p = pos[i];
    float  v = vel_chan[i];
    float  f = flux[i];

    int ix0 = (int)floorf((p.x + FOV_HALF) * INV_PIX);
    int iy0 = (int)floorf((p.y + FOV_HALF) * INV_PIX);
    int iv0 = (int)floorf((v - vel0) / dv);

    const int margin = 4;
    bool mask = (ix0 >= -margin) && (ix0 < N_PIX + margin)
             && (iy0 >= -margin) && (iy0 < N_PIX + margin)
             && (iv0 >= 0) && (iv0 < NV);
    if (!mask) return;

    int idx = (iv0 * N_PIX + iy0) * N_PIX + ix0;
    if (idx >= 0 && idx < CUBE_ELEMS)
        atomicAdd(cube + idx, f);
}

// ---------------- separable 7x7 conv, full-row tiles ----------------
// Per block: one velocity channel, 64 output rows x full 1024-wide row.
// Per iteration: stage next raw row (global_load_lds dwordx4) into a 2-deep
// LDS ring, horizontal-filter it (3 aligned ds_read_b128 -> 12 floats -> 4
// outputs/thread), keep a rolling 7-row float4 window in registers for the
// vertical pass. LDS ops: ~0.8/pixel vs 14/pixel in R3 (which was
// LDS-issue-bound at 2.1 TB/s).
#define CONV_H 64
#define RING 2
#define ROWP (N_PIX + 8)   // [0..3]=0 pad, [4..1027]=row data, [1028..1031]=0 pad

__global__ __launch_bounds__(256) void conv7x7_roll(
    const float* __restrict__ cube,
    const float* __restrict__ k2d,
    float* __restrict__ out)
{
    __shared__ float rows[RING][ROWP];

    // Recover 1-D kernel from row 3 of k2d: k2d[3][j] = g3*g[j], k2d[3][3]=g3^2.
    float g[7];
    {
        float g3 = sqrtf(k2d[24]);
        #pragma unroll
        for (int j = 0; j < 7; ++j) g[j] = k2d[21 + j] / g3;
    }

    const int t  = threadIdx.x;                 // 0..255; owns x = 4t..4t+3
    const int y0 = blockIdx.x * CONV_H;
    const float* __restrict__ src = cube + (size_t)blockIdx.y * (N_PIX * N_PIX);
    float*       __restrict__ dst = out  + (size_t)blockIdx.y * (N_PIX * N_PIX);

    // Zero the 4+4 pad floats of both ring slots (never overwritten after).
    if (t < 16) {
        int s = t >> 3, j = t & 7;
        rows[s][j < 4 ? j : (N_PIX + j)] = 0.0f;
    }

    // Stage raw row gy into ring slot s. Lane writes padded idx [4+4t .. 4+4t+3]
    // = byte (16 + 16t): wave-uniform base + lane*16 as global_load_lds needs.
    auto stage = [&](int gy, int s) {
        if (gy >= 0 && gy < N_PIX) {
            const float* gp = src + (size_t)gy * N_PIX + 4 * t;
            __builtin_amdgcn_global_load_lds(
                (const __attribute__((address_space(1))) void*)gp,
                (__attribute__((address_space(3))) void*)&rows[s][4 + 4 * t],
                16, 0, 0);
        } else {
            float4 z = make_float4(0.f, 0.f, 0.f, 0.f);
            *(float4*)&rows[s][4 + 4 * t] = z;   // ds_write_b128
        }
    };

    // Horizontal filter of ring slot s for this thread's 4-wide strip.
    // Padded idx p holds x = p-4; need x in [4t-3 .. 4t+6] -> p in [4t+1..4t+10]
    // covered by aligned b128 reads at p = 4t, 4t+4, 4t+8.
    auto hf = [&](int s) -> float4 {
        float4 a = *(const float4*)&rows[s][4 * t];
        float4 b = *(const float4*)&rows[s][4 * t + 4];
        float4 c = *(const float4*)&rows[s][4 * t + 8];
        float r[12] = {a.x, a.y, a.z, a.w, b.x, b.y, b.z, b.w, c.x, c.y, c.z, c.w};
        float4 h;
        float s0 = 0.f, s1 = 0.f, s2 = 0.f, s3 = 0.f;
        #pragma unroll
        for (int j = 0; j < 7; ++j) {
            s0 = fmaf(r[1 + j], g[j], s0);
            s1 = fmaf(r[2 + j], g[j], s1);
            s2 = fmaf(r[3 + j], g[j], s2);
            s3 = fmaf(r[4 + j], g[j], s3);
        }
        h.x = s0; h.y = s1; h.z = s2; h.w = s3;
        return h;
    };

    // h[(gy - y0 + 3) & 7] holds the horizontally-filtered row gy (float4 strip).
    float4 h[8];

    // Warmup: rows y0-3 .. y0+2 -> h[0..5].
    for (int w = 0; w < 6; ++w) {
        stage(y0 - 3 + w, w & 1);
        __syncthreads();
        h[w] = hf(w & 1);
    }

    float* dp = dst + (size_t)y0 * N_PIX + 4 * t;
    #pragma unroll 8
    for (int r = 0; r < CONV_H; ++r) {
        stage(y0 + r + 3, r & 1);        // slot parity (r+6)&1 == r&1
        __syncthreads();
        h[(r + 6) & 7] = hf(r & 1);

        float x0a = 0.f, x1a = 0.f, x2a = 0.f, x3a = 0.f;
        #pragma unroll
        for (int k = 0; k < 7; ++k) {
            float4 hk = h[(r + k) & 7];  // hbuf row y0+r-3+k
            x0a = fmaf(hk.x, g[k], x0a);
            x1a = fmaf(hk.y, g[k], x1a);
            x2a = fmaf(hk.z, g[k], x2a);
            x3a = fmaf(hk.w, g[k], x3a);
        }
        float4 o; o.x = x0a; o.y = x1a; o.z = x2a; o.w = x3a;
        *(float4*)dp = o;                // coalesced global_store_dwordx4
        dp += N_PIX;
    }
}

extern "C" void kernel_launch(void* const* d_in, const int* in_sizes, int n_in,
                              void* d_out, int out_size, void* d_ws, size_t ws_size,
                              hipStream_t stream)
{
    const float2* pos      = (const float2*)d_in[0];
    const float*  vel_chan = (const float*)d_in[1];
    const float*  flux     = (const float*)d_in[2];
    const float*  vel_axis = (const float*)d_in[3];
    const float*  k2d      = (const float*)d_in[4];
    float* cube = (float*)d_ws;
    float* out  = (float*)d_out;

    const int M = in_sizes[1];  // 1,600,000 points

    hipMemsetAsync(cube, 0, (size_t)CUBE_ELEMS * sizeof(float), stream);

    splat_scatter<<<(M + 255) / 256, 256, 0, stream>>>(
        pos, vel_chan, flux, vel_axis, cube, M);

    dim3 grid(N_PIX / CONV_H, NV);
    conv7x7_roll<<<grid, 256, 0, stream>>>(cube, k2d, out);
}